// Round 6
// baseline (267.754 us; speedup 1.0000x reference)
//
#include <hip/hip_runtime.h>
#include <hip/hip_bf16.h>

typedef __attribute__((ext_vector_type(4))) float  f32x4;
typedef __attribute__((ext_vector_type(8))) short  s16x8;
typedef __attribute__((ext_vector_type(4))) short  s16x4;
typedef unsigned short u16;

constexpr int B_  = 4;
constexpr int S_  = 2048;
constexpr int D_  = 1024;
constexpr int H_  = 16;
constexpr int Dh_ = 64;

// 1/sqrt(Dh) * log2(e) folded into Q at projection time
#define QSCALE 0.18033688f

static __device__ __forceinline__ short fb(float f) {
    __hip_bfloat16 h = __float2bfloat16(f);
    return __builtin_bit_cast(short, h);
}

static __device__ __forceinline__ void gload16(const u16* g, u16* l) {
    __builtin_amdgcn_global_load_lds(
        (const __attribute__((address_space(1))) unsigned int*)g,
        (__attribute__((address_space(3))) unsigned int*)l, 16, 0, 0);
}

// ---------------------------------------------------------------------------
// f32 -> bf16 convert (weights), 8 elems/thread
// ---------------------------------------------------------------------------
__global__ __launch_bounds__(256)
void cvtW(const float* __restrict__ s0, const float* __restrict__ s1,
          const float* __restrict__ s2,
          u16* __restrict__ d0, u16* __restrict__ d1, u16* __restrict__ d2)
{
    const float* s = blockIdx.y == 0 ? s0 : (blockIdx.y == 1 ? s1 : s2);
    u16*         d = blockIdx.y == 0 ? d0 : (blockIdx.y == 1 ? d1 : d2);
    long i = ((long)blockIdx.x * 256 + threadIdx.x) * 8;
    f32x4 a = *(const f32x4*)(s + i), b = *(const f32x4*)(s + i + 4);
    s16x8 o;
    #pragma unroll
    for (int j = 0; j < 4; ++j) { o[j] = fb(a[j]); o[4 + j] = fb(b[j]); }
    *(s16x8*)(d + i) = o;
}

// ---------------------------------------------------------------------------
// NT GEMM: C[m,n] = sum_k A[m,k]*W[n,k]; M=8192, N=K=1024. 128x128 tile, BK=32.
// MODE 0: C -> bf16 [B,H,S,Dh] * oscale            (Q projection)
// MODE 3: C -> bf16 K-tiles [bh][kb][r][swz]        (K, pre-swizzled for LDS)
// MODE 2: C -> bf16 V^T-tiles [bh][kb][dh][swz]     (V, pre-swizzled for LDS)
// MODE 1: C -> f32 [M,N]                            (output projection)
// ---------------------------------------------------------------------------
template <int MODE>
__global__ __launch_bounds__(256)
void gemm_bf(const void* __restrict__ Av, const u16* __restrict__ Wb,
             void* __restrict__ Cv, float oscale)
{
    __shared__ u16 As[128 * 32];
    __shared__ u16 Bs[128 * 32];

    const int m0 = blockIdx.y * 128, n0 = blockIdx.x * 128;
    const int t = threadIdx.x, lane = t & 63, w = t >> 6;
    const int wr = (w >> 1) * 64, wc = (w & 1) * 64;
    const int lr = lane & 15, lg = lane >> 4;

    const int srow = t >> 2;                         // 0..63
    const int cc   = (t & 3) ^ ((t >> 3) & 3);       // swizzled 16B chunk
    const int fcol = (lg ^ ((lr >> 1) & 3)) * 8;     // swizzled read col

    const u16* Brow = Wb + (long)(n0 + srow) * 1024 + cc * 8;
    f32x4 acc[4][4] = {};

    for (int k0 = 0; k0 < 1024; k0 += 32) {
        gload16(Brow + k0,             Bs + w * 512);
        gload16(Brow + 64 * 1024 + k0, Bs + 2048 + w * 512);
        if (MODE == 1) {
            const u16* Arow = (const u16*)Av + (long)(m0 + srow) * 1024 + cc * 8;
            gload16(Arow + k0,             As + w * 512);
            gload16(Arow + 64 * 1024 + k0, As + 2048 + w * 512);
        } else {
            const float* Af = (const float*)Av + (long)(m0 + srow) * 1024 + (t & 3) * 8;
            #pragma unroll
            for (int c = 0; c < 2; ++c) {
                const float* p = Af + (long)c * 64 * 1024 + k0;
                f32x4 a = *(const f32x4*)(p), b = *(const f32x4*)(p + 4);
                s16x8 o;
                #pragma unroll
                for (int j = 0; j < 4; ++j) { o[j] = fb(a[j]); o[4 + j] = fb(b[j]); }
                *(s16x8*)(&As[(c * 64 + srow) * 32 + cc * 8]) = o;
            }
        }
        __syncthreads();

        s16x8 af[4], bfr[4];
        #pragma unroll
        for (int i = 0; i < 4; ++i)
            af[i] = *(const s16x8*)(&As[(wr + i * 16 + lr) * 32 + fcol]);
        #pragma unroll
        for (int i = 0; i < 4; ++i)
            bfr[i] = *(const s16x8*)(&Bs[(wc + i * 16 + lr) * 32 + fcol]);
        #pragma unroll
        for (int mi = 0; mi < 4; ++mi)
            #pragma unroll
            for (int ni = 0; ni < 4; ++ni)
                acc[mi][ni] = __builtin_amdgcn_mfma_f32_16x16x32_bf16(
                    af[mi], bfr[ni], acc[mi][ni], 0, 0, 0);
        __syncthreads();
    }

    if (MODE == 0) {
        u16* Cb = (u16*)Cv;                          // [B,H,S,Dh]
        #pragma unroll
        for (int mi = 0; mi < 4; ++mi)
            #pragma unroll
            for (int ni = 0; ni < 4; ++ni) {
                int col = n0 + wc + ni * 16 + lr;
                int h = col >> 6, dh = col & 63;
                #pragma unroll
                for (int r = 0; r < 4; ++r) {
                    int row = m0 + wr + mi * 16 + lg * 4 + r;
                    int b = row >> 11, s = row & 2047;
                    Cb[(((long)b * H_ + h) * S_ + s) * Dh_ + dh] =
                        (u16)fb(acc[mi][ni][r] * oscale);
                }
            }
    } else if (MODE == 3) {
        u16* Cb = (u16*)Cv;                          // K swizzled tiles
        #pragma unroll
        for (int mi = 0; mi < 4; ++mi)
            #pragma unroll
            for (int ni = 0; ni < 4; ++ni) {
                int col = n0 + wc + ni * 16 + lr;
                int h = col >> 6, dh = col & 63;
                #pragma unroll
                for (int r = 0; r < 4; ++r) {
                    int row = m0 + wr + mi * 16 + lg * 4 + r;
                    int b = row >> 11, s = row & 2047;
                    long idx = ((long)(b * H_ + h)) * 131072 + ((long)(s >> 6) << 12)
                             + ((s & 63) << 6) + (((dh >> 3) ^ (s & 7)) << 3) + (dh & 7);
                    Cb[idx] = (u16)fb(acc[mi][ni][r]);
                }
            }
    } else if (MODE == 2) {
        u16* Cb = (u16*)Cv;                          // V^T swizzled tiles
        #pragma unroll
        for (int mi = 0; mi < 4; ++mi)
            #pragma unroll
            for (int ni = 0; ni < 4; ++ni) {
                int col = n0 + wc + ni * 16 + lr;
                int h = col >> 6, dh = col & 63;
                int row = m0 + wr + mi * 16 + lg * 4;     // 4 consecutive tokens
                int b = row >> 11, k = row & 2047;
                long idx = ((long)(b * H_ + h)) * 131072 + ((long)(k >> 6) << 12)
                         + (dh << 6) + ((((k >> 3) & 7) ^ (dh & 7)) << 3) + (k & 7);
                union { short h4[4]; unsigned long long u; } pk;
                #pragma unroll
                for (int r = 0; r < 4; ++r) pk.h4[r] = fb(acc[mi][ni][r]);
                *(unsigned long long*)(&Cb[idx]) = pk.u;
            }
    } else {
        float* C = (float*)Cv;                       // [M,1024] f32
        #pragma unroll
        for (int mi = 0; mi < 4; ++mi)
            #pragma unroll
            for (int ni = 0; ni < 4; ++ni) {
                int col = n0 + wc + ni * 16 + lr;
                #pragma unroll
                for (int r = 0; r < 4; ++r) {
                    int row = m0 + wr + mi * 16 + lg * 4 + r;
                    C[(long)row * 1024 + col] = acc[mi][ni][r];
                }
            }
    }
}

// ---------------------------------------------------------------------------
// Causal flash attention v6: LDS-staged block-flash, single-strip blocks.
// 1 block = 8 waves (512 thr) = 256 q-rows of one (b,h). Grid = 512 blocks,
// ALL co-resident (2 blocks/CU = 16 waves/CU; LDS 64KB/CU, VGPR ~76).
// Dispatch order pairs complementary strips per CU: rank r<4 -> qb=7-r,
// else qb=r-4  =>  each CU gets (7-r, 3-r') style pair, uniform 36 kb-units.
// Per 64-key block: K/V^T tiles staged via global_load_lds from pre-swizzled
// ws, double-buffered; per-lane lrun partials (cross-lane reduce only in
// epilogue); triplet max tree (v_max3).
// ---------------------------------------------------------------------------
__global__ __launch_bounds__(512)
void attn(const u16* __restrict__ Qp, const u16* __restrict__ Kws,
          const u16* __restrict__ Vws, u16* __restrict__ Op)
{
    __shared__ u16 Klds[2][4096];
    __shared__ u16 Vlds[2][4096];

    const int t = threadIdx.x, lane = t & 63, w = t >> 6;
    const int lr = lane & 15, lg = lane >> 4;
    const int bh = blockIdx.x & 63;
    const int r  = blockIdx.x >> 6;               // 0..7
    const int qb = (r < 4) ? (7 - r) : (r - 4);   // complementary pairing
    const int b = bh >> 4, h = bh & 15;

    const u16* Kb = Kws + (long)bh * 131072;
    const u16* Vb = Vws + (long)bh * 131072;

    const int q0w = qb * 256 + w * 32;
    const u16* Qbp = Qp + ((long)bh * S_ + q0w) * Dh_;

    s16x8 qf[2][2];
    #pragma unroll
    for (int i = 0; i < 2; ++i)
        #pragma unroll
        for (int hh = 0; hh < 2; ++hh)
            qf[i][hh] = *(const s16x8*)(Qbp + (i * 16 + lr) * Dh_ + hh * 32 + lg * 8);

    f32x4 acc[2][4] = {};
    float mrun[2] = { -1e30f, -1e30f }, lrun[2] = { 0.0f, 0.0f };  // lrun per-lane partial
    const int nkb = (qb + 1) * 4;

    // prologue: stage kb=0 (each wave stages 1KB of K and 1KB of V)
    gload16(Kb + w * 512 + lane * 8, &Klds[0][w * 512]);
    gload16(Vb + w * 512 + lane * 8, &Vlds[0][w * 512]);
    __syncthreads();

    #pragma unroll 1
    for (int kb = 0; kb < nkb; ++kb) {
        const int cur = kb & 1;
        const int k0 = kb * 64;
        if (kb + 1 < nkb) {
            const long off = (long)(kb + 1) * 4096 + w * 512 + lane * 8;
            gload16(Kb + off, &Klds[cur ^ 1][w * 512]);
            gload16(Vb + off, &Vlds[cur ^ 1][w * 512]);
        }
        if (k0 <= q0w + 31) {
            // ---- QK^T from swizzled K tile ----
            f32x4 st[2][4] = {};
            const int r7 = lr & 7;
            __builtin_amdgcn_s_setprio(1);
            #pragma unroll
            for (int kt = 0; kt < 4; ++kt) {
                const int rb = (kt * 16 + lr) * 64;
                s16x8 kf0 = *(const s16x8*)(&Klds[cur][rb + ((lg ^ r7) << 3)]);
                s16x8 kf1 = *(const s16x8*)(&Klds[cur][rb + (((4 + lg) ^ r7) << 3)]);
                #pragma unroll
                for (int i = 0; i < 2; ++i) {
                    st[i][kt] = __builtin_amdgcn_mfma_f32_16x16x32_bf16(
                        kf0, qf[i][0], st[i][kt], 0, 0, 0);
                    st[i][kt] = __builtin_amdgcn_mfma_f32_16x16x32_bf16(
                        kf1, qf[i][1], st[i][kt], 0, 0, 0);
                }
            }
            __builtin_amdgcn_s_setprio(0);

            // ---- softmax (exp2 domain, deferred max, per-lane psum) ----
            const bool dmask = (k0 + 63) > q0w;
            s16x4 pb[2][4];
            #pragma unroll
            for (int i = 0; i < 2; ++i) {
                const int qg = q0w + i * 16 + lr;
                float sv[16];
                #pragma unroll
                for (int kt = 0; kt < 4; ++kt)
                    #pragma unroll
                    for (int rr = 0; rr < 4; ++rr) {
                        float sc = st[i][kt][rr];
                        if (dmask && (k0 + kt * 16 + lg * 4 + rr) > qg) sc = -1e30f;
                        sv[kt * 4 + rr] = sc;
                    }
                // triplet max tree -> v_max3
                float t0 = fmaxf(fmaxf(sv[0], sv[1]), sv[2]);
                float t1 = fmaxf(fmaxf(sv[3], sv[4]), sv[5]);
                float t2 = fmaxf(fmaxf(sv[6], sv[7]), sv[8]);
                float t3 = fmaxf(fmaxf(sv[9], sv[10]), sv[11]);
                float t4 = fmaxf(fmaxf(sv[12], sv[13]), sv[14]);
                float tm = fmaxf(fmaxf(fmaxf(t0, t1), t2),
                                 fmaxf(fmaxf(t3, t4), sv[15]));
                tm = fmaxf(tm, __shfl_xor(tm, 16));
                tm = fmaxf(tm, __shfl_xor(tm, 32));
                float mnew = mrun[i];
                if (!__all(tm <= mrun[i] + 8.0f)) {      // T13 defer-max
                    mnew = fmaxf(mrun[i], tm);
                    float f = __builtin_amdgcn_exp2f(mrun[i] - mnew);
                    lrun[i] *= f;
                    #pragma unroll
                    for (int tt = 0; tt < 4; ++tt) acc[i][tt] *= f;
                    mrun[i] = mnew;
                }
                float psum = 0.0f;
                #pragma unroll
                for (int kt = 0; kt < 4; ++kt) {
                    short ph[4];
                    #pragma unroll
                    for (int rr = 0; rr < 4; ++rr) {
                        float p = __builtin_amdgcn_exp2f(sv[kt * 4 + rr] - mnew);
                        psum += p;
                        ph[rr] = fb(p);
                    }
                    pb[i][kt] = (s16x4){ ph[0], ph[1], ph[2], ph[3] };
                }
                lrun[i] += psum;                     // per-lane partial
            }

            // ---- PV from swizzled V^T tile ----
            __builtin_amdgcn_s_setprio(1);
            #pragma unroll
            for (int kt = 0; kt < 4; ++kt)
                #pragma unroll
                for (int tt = 0; tt < 4; ++tt) {
                    const int rb = (tt * 16 + lr) * 64;
                    const int gsw = (kt * 2 + (lg >> 1)) ^ r7;
                    s16x4 vf = *(const s16x4*)
                        (&Vlds[cur][rb + (gsw << 3) + ((lg & 1) << 2)]);
                    acc[0][tt] = __builtin_amdgcn_mfma_f32_16x16x16bf16_1k(
                        vf, pb[0][kt], acc[0][tt], 0, 0, 0);
                    acc[1][tt] = __builtin_amdgcn_mfma_f32_16x16x16bf16_1k(
                        vf, pb[1][kt], acc[1][tt], 0, 0, 0);
                }
            __builtin_amdgcn_s_setprio(0);
        }
        __syncthreads();
    }

    // ---- epilogue: reduce lrun across the row's 4 lanes, write O ----
    #pragma unroll
    for (int i = 0; i < 2; ++i) {
        float l = lrun[i];
        l += __shfl_xor(l, 16);
        l += __shfl_xor(l, 32);
        const float inv = 1.0f / l;
        u16* ob = Op + (((long)b * S_ + q0w + i * 16 + lr) * H_ + h) * Dh_;
        #pragma unroll
        for (int tt = 0; tt < 4; ++tt) {
            union { short h4[4]; unsigned long long u; } pk;
            #pragma unroll
            for (int rr = 0; rr < 4; ++rr) pk.h4[rr] = fb(acc[i][tt][rr] * inv);
            *(unsigned long long*)(ob + tt * 16 + lg * 4) = pk.u;
        }
    }
}

// ---------------------------------------------------------------------------
extern "C" void kernel_launch(void* const* d_in, const int* in_sizes, int n_in,
                              void* d_out, int out_size, void* d_ws, size_t ws_size,
                              hipStream_t stream)
{
    const float* q  = (const float*)d_in[0];
    const float* k  = (const float*)d_in[1];
    const float* v  = (const float*)d_in[2];
    // d_in[3] = causal mask — hardcoded
    const float* Wq = (const float*)d_in[4];
    const float* Wk = (const float*)d_in[5];
    const float* Wv = (const float*)d_in[6];
    const float* Wo = (const float*)d_in[7];

    u16* ws = (u16*)d_ws;
    const long NE = (long)B_ * S_ * D_;           // 8388608 elems
    const long WE = (long)D_ * D_;                // 1048576 elems
    u16* Qp  = ws;                                 // [B,H,S,Dh]
    u16* Kws_ = ws + NE;                           // K swizzled tiles
    u16* Vws_ = ws + 2 * NE;                       // V^T swizzled tiles
    u16* Op  = ws + 3 * NE;                        // [B,S,H,Dh]
    u16* WqB = Op;            // dead before attn writes Op
    u16* WkB = Op + WE;
    u16* WvB = Op + 2 * WE;
    u16* WoB = Qp;            // Qp dead after attn

    dim3 gw(512, 3), gw1(512, 1), gg(8, 64), blk(256);
    hipLaunchKernelGGL(cvtW, gw, blk, 0, stream, Wq, Wk, Wv, WqB, WkB, WvB);
    hipLaunchKernelGGL((gemm_bf<0>), gg, blk, 0, stream, q, WqB, Qp, QSCALE);
    hipLaunchKernelGGL((gemm_bf<3>), gg, blk, 0, stream, k, WkB, Kws_, 1.0f);
    hipLaunchKernelGGL((gemm_bf<2>), gg, blk, 0, stream, v, WvB, Vws_, 1.0f);
    hipLaunchKernelGGL(attn, dim3(512), dim3(512), 0, stream, Qp, Kws_, Vws_, Op);
    hipLaunchKernelGGL(cvtW, gw1, blk, 0, stream, Wo, Wo, Wo, WoB, WoB, WoB);
    hipLaunchKernelGGL((gemm_bf<1>), gg, blk, 0, stream, Op, WoB, (float*)d_out, 1.0f);
}